// Round 5
// baseline (1395.096 us; speedup 1.0000x reference)
//
#include <hip/hip_runtime.h>
#include <math.h>

#define NB 8
#define NA 32
#define NCELL 256
#define NPAIR 496
#define SLOT 496          // max triplets per cell
#define FST 10            // 9 features + weight
#define TC 16             // triplets per chunk
#define XS 20             // padded activation row stride (floats)
#define NQ 8              // chunk-slots per cell
#define CUTOFF_F 3.5f
#define EPS_F 1e-7f
#define CLIP_MIN_F 1e-10f
#define PI_F 3.14159274101257324f   // float32(np.pi)

// ---------------- K1: compact active triplets, compute features ----------------
__global__ __launch_bounds__(256) void aev_feat(
    const float* __restrict__ D, const float* __restrict__ S,
    float* __restrict__ feat, int* __restrict__ count, float* __restrict__ GA)
{
    __shared__ float Dm[NA][NA];
    __shared__ float Sv[NA];
    __shared__ int s_T;
    const int tid = threadIdx.x;
    const int cell = blockIdx.x;
    const int b = cell >> 5, i = cell & 31;

    for (int idx = tid; idx < NA * NA; idx += 256)
        ((float*)Dm)[idx] = D[b * NA * NA + idx];
    if (tid < NA) Sv[tid] = S[b * NA + tid];
    if (tid == 0) s_T = 0;
    GA[cell * 256 + tid] = 0.f;
    __syncthreads();

    for (int p = tid; p < NPAIR; p += 256) {
        int rem = p, j = 0;
        while (rem >= 31 - j) { rem -= 31 - j; ++j; }
        const int k = j + 1 + rem;
        const float dij = Dm[i][j], dik = Dm[i][k];
        if (dij < CUTOFF_F && dij != 0.f && dik < CUTOFF_F && dik != 0.f) {
            const int slot = atomicAdd(&s_T, 1);
            const float Rij = dij, Rik = dik, Rjk = Dm[j][k];
            const float zi = Sv[i], zj = Sv[j], zk = Sv[k];
            const float ci = (Rij*Rij + Rik*Rik - Rjk*Rjk) / fmaxf(2.f*Rij*Rik, CLIP_MIN_F);
            const float cj = (Rij*Rij + Rjk*Rjk - Rik*Rik) / fmaxf(2.f*Rij*Rjk, CLIP_MIN_F);
            const float ck = (Rik*Rik + Rjk*Rjk - Rij*Rij) / fmaxf(2.f*Rik*Rjk, CLIP_MIN_F);
            float g0 = Rij + Rik + Rjk;
            float g1 = Rij*Rik + Rij*Rjk + Rik*Rjk;
            float g2 = Rij*Rik*Rjk;
            const float gn = sqrtf(g0*g0 + g1*g1 + g2*g2) + EPS_F;
            float h0 = zi + zj + zk;
            float h1 = ci + cj + ck;
            float h2 = zi*(zj + zk) + zj*zk - ci*(cj + ck) - cj*ck;
            float h3 = zi*(cj + ck) + ci*(zj + zk) + zj*ck + cj*zk;
            float h4 = zi*(zj*zk - cj*ck) - ci*(zj*ck + cj*zk);
            float h5 = zi*(zj*ck + cj*zk) + ci*(zj*zk - cj*ck);
            const float hn = sqrtf(h0*h0 + h1*h1 + h2*h2 + h3*h3 + h4*h4 + h5*h5) + EPS_F;
            const float fcij = 0.5f * cosf(PI_F * Rij / CUTOFF_F) + 0.5f;
            const float fcik = 0.5f * cosf(PI_F * Rik / CUTOFF_F) + 0.5f;
            float* fp = &feat[(cell * SLOT + slot) * FST];
            fp[0] = g0 / gn; fp[1] = g1 / gn; fp[2] = g2 / gn;
            fp[3] = h0 / hn; fp[4] = h1 / hn; fp[5] = h2 / hn;
            fp[6] = h3 / hn; fp[7] = h4 / hn; fp[8] = h5 / hn;
            fp[9] = fcij * fcik;
        }
    }
    __syncthreads();
    if (tid == 0) count[cell] = s_T;
}

// -------- async global->LDS staging (no VGPR payload) --------
__device__ __forceinline__ void cp_async16(const float* g, float* l) {
    __builtin_amdgcn_global_load_lds(
        (const __attribute__((address_space(1))) unsigned int*)g,
        (__attribute__((address_space(3))) unsigned int*)l, 16, 0, 0);
}

// stage one 4096-float (16KB) slice: 4 waves x 4 issues x (64 lanes x 16B)
__device__ __forceinline__ void stage16k(const float* __restrict__ g,
                                         float* __restrict__ buf, int tid) {
    const int lane = tid & 63, w = tid >> 6;
#pragma unroll
    for (int r = 0; r < 4; ++r) {
        const int off = (w * 4 + r) * 256;
        cp_async16(g + off + lane * 4, buf + off);   // LDS base wave-uniform
    }
}

// -------- layer computes (weights + bias from LDS) --------
// 64-out layer: thread = 1 feature x 4 triplets.
template<int K, bool RES>
__device__ __forceinline__ void compute64(
    const float* __restrict__ Wl, const float* __restrict__ bl,
    const float* __restrict__ X, float* __restrict__ Y,
    const float* __restrict__ R, int tid)
{
    const int fi = tid & 63;
    const int xo = (tid >> 6) * 4;
    const float bb = bl[fi];
    float a0 = bb, a1 = bb, a2 = bb, a3 = bb;
#pragma unroll
    for (int k = 0; k < K; ++k) {
        const float4 xv = *(const float4*)&X[k * XS + xo];   // wave-broadcast
        const float w = Wl[k * 64 + fi];
        a0 += xv.x * w; a1 += xv.y * w; a2 += xv.z * w; a3 += xv.w * w;
    }
    float4 y;
    y.x = tanhf(a0); y.y = tanhf(a1); y.z = tanhf(a2); y.w = tanhf(a3);
    if (RES) {
        const float4 r = *(const float4*)&R[fi * XS + xo];
        y.x += r.x; y.y += r.y; y.z += r.z; y.w += r.w;
    }
    *(float4*)&Y[fi * XS + xo] = y;
}

// 64->128 layer, one 32-row k-slice. Thread = outputs (fo, fo+64) x 4 triplets.
__device__ __forceinline__ void compute5_part(
    const float* __restrict__ Wl /*32 rows x 128*/, const float* __restrict__ X,
    int k0, float (&a0)[4], float (&a1)[4], int tid)
{
    const int fo = tid & 63;
    const int xo = (tid >> 6) * 4;
#pragma unroll
    for (int k = 0; k < 32; ++k) {
        const float4 xv = *(const float4*)&X[(k0 + k) * XS + xo];
        const float w0 = Wl[k * 128 + fo];
        const float w1 = Wl[k * 128 + fo + 64];
        a0[0] += xv.x * w0; a0[1] += xv.y * w0; a0[2] += xv.z * w0; a0[3] += xv.w * w0;
        a1[0] += xv.x * w1; a1[1] += xv.y * w1; a1[2] += xv.z * w1; a1[3] += xv.w * w1;
    }
}

// 128->256 layer, one 16-row k-slice. Thread = output f=tid, all 16 triplets.
__device__ __forceinline__ void compute6_part(
    const float* __restrict__ Wl /*16 rows x 256*/, const float* __restrict__ X,
    int k0, float (&a)[16], int tid)
{
#pragma unroll
    for (int k = 0; k < 16; ++k) {
        const float w = Wl[k * 256 + tid];
        const float4 x0 = *(const float4*)&X[(k0 + k) * XS + 0];
        const float4 x1 = *(const float4*)&X[(k0 + k) * XS + 4];
        const float4 x2 = *(const float4*)&X[(k0 + k) * XS + 8];
        const float4 x3 = *(const float4*)&X[(k0 + k) * XS + 12];
        a[0]  += x0.x * w; a[1]  += x0.y * w; a[2]  += x0.z * w; a[3]  += x0.w * w;
        a[4]  += x1.x * w; a[5]  += x1.y * w; a[6]  += x1.z * w; a[7]  += x1.w * w;
        a[8]  += x2.x * w; a[9]  += x2.y * w; a[10] += x2.z * w; a[11] += x2.w * w;
        a[12] += x3.x * w; a[13] += x3.y * w; a[14] += x3.z * w; a[15] += x3.w * w;
    }
}

// ---------------- K2: async-pipelined MLP (3-buffer rotation) ----------------
// Schedule: phase i consumes slice s_i from buf[i%3], issues s_{i+2} into
// buf[(i+2)%3] (whose content was consumed at phase i-1, one barrier back).
__global__ __launch_bounds__(256) void aev_mlp(
    const float* __restrict__ feat, const int* __restrict__ count,
    const float* __restrict__ W0, const float* __restrict__ b0,
    const float* __restrict__ W1, const float* __restrict__ b1,
    const float* __restrict__ W2, const float* __restrict__ b2,
    const float* __restrict__ W3, const float* __restrict__ b3,
    const float* __restrict__ W4, const float* __restrict__ b4,
    const float* __restrict__ W5, const float* __restrict__ b5,
    const float* __restrict__ W6, const float* __restrict__ b6,
    float* __restrict__ GA)
{
    __shared__ __align__(16) float WB0[4096];
    __shared__ __align__(16) float WB1[4096];
    __shared__ __align__(16) float WB2[4096];
    __shared__ __align__(16) float Xs[9 * XS];
    __shared__ __align__(16) float U0[64 * XS];
    __shared__ __align__(16) float U1[64 * XS];
    __shared__ __align__(16) float U2[64 * XS];
    __shared__ __align__(16) float U3[128 * XS];
    __shared__ float wsh[TC];
    __shared__ float bsh[704];   // b0..b4 @0..319, b5 @320, b6 @448

    const int tid = threadIdx.x;
    const int cell = blockIdx.x & 255;
    const int q = blockIdx.x >> 8;
    const int T = count[cell];
    const int nch = (T + TC - 1) / TC;
    if (q >= nch) return;        // block-uniform exit (no barriers yet)

    if (tid < 64) {
        bsh[tid]       = b0[tid];
        bsh[64 + tid]  = b1[tid];
        bsh[128 + tid] = b2[tid];
        bsh[192 + tid] = b3[tid];
        bsh[256 + tid] = b4[tid];
    }
    if (tid < 128) bsh[320 + tid] = b5[tid];
    bsh[448 + tid] = b6[tid];

    float gacc = 0.f;

    for (int c = q; c < nch; c += NQ) {
        const int t0 = c * TC;

        // ---- prologue: W0->WB0 (sync, 2.3KB), issue W1->WB1, load features ----
        stage16k(W1, WB1, tid);
        if (tid < 144) ((float4*)WB0)[tid] = ((const float4*)W0)[tid];
        if (tid < TC * FST) {   // contiguous 160 floats
            const int t = tid / FST, qf = tid % FST;
            const int slot = t0 + t;
            const float v = (slot < T) ? feat[(cell * SLOT + t0) * FST + tid] : 0.f;
            if (qf == 9) wsh[t] = v; else Xs[qf * XS + t] = v;
        }
        __syncthreads();

        // ph0: L0 (WB0); issue W2->WB2
        stage16k(W2, WB2, tid);
        compute64<9,  false>(WB0, bsh + 0,   Xs, U0, nullptr, tid);
        __syncthreads();
        // ph1: L1 (WB1, res U0); issue W3->WB0
        stage16k(W3, WB0, tid);
        compute64<64, true >(WB1, bsh + 64,  U0, U1, U0, tid);       // xb1 -> U1
        __syncthreads();
        // ph2: L2 (WB2); issue W4->WB1
        stage16k(W4, WB1, tid);
        compute64<64, false>(WB2, bsh + 128, U1, U2, nullptr, tid);  // x2 -> U2
        __syncthreads();
        // ph3: L3 (WB0); issue W5a->WB2
        stage16k(W5, WB2, tid);
        compute64<64, false>(WB0, bsh + 192, U2, U0, nullptr, tid);  // x3 -> U0
        __syncthreads();
        // ph4: L4 (WB1, res U1); issue W5b->WB0
        stage16k(W5 + 4096, WB0, tid);
        compute64<64, true >(WB1, bsh + 256, U0, U2, U1, tid);       // xb2 -> U2
        __syncthreads();

        // ---- L5: 2 k-slices, persistent accumulators ----
        float a0[4], a1[4];
        {
            const int fo = tid & 63;
            const float bb0 = bsh[320 + fo], bb1 = bsh[320 + fo + 64];
#pragma unroll
            for (int r = 0; r < 4; ++r) { a0[r] = bb0; a1[r] = bb1; }
        }
        // ph5: L5a (WB2); issue W6 s0->WB1
        stage16k(W6, WB1, tid);
        compute5_part(WB2, U2, 0, a0, a1, tid);
        __syncthreads();
        // ph6: L5b (WB0), tanh -> U3; issue W6 s1->WB2
        stage16k(W6 + 4096, WB2, tid);
        compute5_part(WB0, U2, 32, a0, a1, tid);
        {
            const int fo = tid & 63;
            const int xo = (tid >> 6) * 4;
            float4 y0, y1;
            y0.x = tanhf(a0[0]); y0.y = tanhf(a0[1]); y0.z = tanhf(a0[2]); y0.w = tanhf(a0[3]);
            y1.x = tanhf(a1[0]); y1.y = tanhf(a1[1]); y1.z = tanhf(a1[2]); y1.w = tanhf(a1[3]);
            *(float4*)&U3[fo * XS + xo] = y0;
            *(float4*)&U3[(fo + 64) * XS + xo] = y1;
        }
        __syncthreads();

        // ---- L6: 8 k-slices of 16 rows; thread = output f=tid x 16 triplets ----
        float a6[16];
        {
            const float bb = bsh[448 + tid];
#pragma unroll
            for (int r = 0; r < 16; ++r) a6[r] = bb;
        }
        // ph7: s0 (WB1); issue s2->WB0
        stage16k(W6 + 2 * 4096, WB0, tid);
        compute6_part(WB1, U3, 0, a6, tid);
        __syncthreads();
        // ph8: s1 (WB2); issue s3->WB1
        stage16k(W6 + 3 * 4096, WB1, tid);
        compute6_part(WB2, U3, 16, a6, tid);
        __syncthreads();
        // ph9: s2 (WB0); issue s4->WB2
        stage16k(W6 + 4 * 4096, WB2, tid);
        compute6_part(WB0, U3, 32, a6, tid);
        __syncthreads();
        // ph10: s3 (WB1); issue s5->WB0
        stage16k(W6 + 5 * 4096, WB0, tid);
        compute6_part(WB1, U3, 48, a6, tid);
        __syncthreads();
        // ph11: s4 (WB2); issue s6->WB1
        stage16k(W6 + 6 * 4096, WB1, tid);
        compute6_part(WB2, U3, 64, a6, tid);
        __syncthreads();
        // ph12: s5 (WB0); issue s7->WB2
        stage16k(W6 + 7 * 4096, WB2, tid);
        compute6_part(WB0, U3, 80, a6, tid);
        __syncthreads();
        // ph13: s6 (WB1)
        compute6_part(WB1, U3, 96, a6, tid);
        __syncthreads();
        // ph14: s7 (WB2)
        compute6_part(WB2, U3, 112, a6, tid);

        // finalize: weighted tanh sum into register accumulator
#pragma unroll
        for (int r = 0; r < 16; ++r)
            gacc += wsh[r] * tanhf(a6[r]);
        __syncthreads();   // protect wsh/Xs/WB1 before next chunk overwrites
    }

    atomicAdd(&GA[cell * 256 + tid], gacc);
}

// ---------------- K3: normalize ----------------
__global__ __launch_bounds__(256) void aev_norm(
    const float* __restrict__ GA, float* __restrict__ out)
{
    __shared__ float wred[4];
    const int tid = threadIdx.x;
    const int cell = blockIdx.x;
    const float v = GA[cell * 256 + tid];
    float ss = v * v;
#pragma unroll
    for (int off = 32; off > 0; off >>= 1) ss += __shfl_down(ss, off);
    if ((tid & 63) == 0) wred[tid >> 6] = ss;
    __syncthreads();
    const float tot = wred[0] + wred[1] + wred[2] + wred[3];
    out[cell * 256 + tid] = v / (sqrtf(tot) + EPS_F);
}

extern "C" void kernel_launch(void* const* d_in, const int* in_sizes, int n_in,
                              void* d_out, int out_size, void* d_ws, size_t ws_size,
                              hipStream_t stream)
{
    const float* D  = (const float*)d_in[0];
    const float* S  = (const float*)d_in[1];
    const float* W0 = (const float*)d_in[2];  const float* b0 = (const float*)d_in[3];
    const float* W1 = (const float*)d_in[4];  const float* b1 = (const float*)d_in[5];
    const float* W2 = (const float*)d_in[6];  const float* b2 = (const float*)d_in[7];
    const float* W3 = (const float*)d_in[8];  const float* b3 = (const float*)d_in[9];
    const float* W4 = (const float*)d_in[10]; const float* b4 = (const float*)d_in[11];
    const float* W5 = (const float*)d_in[12]; const float* b5 = (const float*)d_in[13];
    const float* W6 = (const float*)d_in[14]; const float* b6 = (const float*)d_in[15];
    float* out = (float*)d_out;

    float* feat  = (float*)d_ws;                        // 256*496*10 floats
    int*   count = (int*)(feat + NCELL * SLOT * FST);   // 256 ints
    float* GA    = (float*)(count + 256);               // 256*256 floats

    aev_feat<<<dim3(NCELL), dim3(256), 0, stream>>>(D, S, feat, count, GA);
    aev_mlp<<<dim3(NCELL * NQ), dim3(256), 0, stream>>>(
        feat, count, W0, b0, W1, b1, W2, b2, W3, b3, W4, b4, W5, b5, W6, b6, GA);
    aev_norm<<<dim3(NCELL), dim3(256), 0, stream>>>(GA, out);
}

// Round 6
// 117.861 us; speedup vs baseline: 11.8368x; 11.8368x over previous
//
#include <hip/hip_runtime.h>
#include <math.h>

#define NB 8
#define NA 32
#define NCELL 256
#define NPAIR 496
#define SLOT 496          // max triplets per cell
#define FST 10            // 9 features + weight
#define TC 16             // triplets per chunk
#define XS 20             // padded activation row stride (floats)
#define NQ 8              // chunk-slots per cell
#define CUTOFF_F 3.5f
#define EPS_F 1e-7f
#define CLIP_MIN_F 1e-10f
#define PI_F 3.14159274101257324f   // float32(np.pi)

// ---------------- K1: compact active triplets, compute features ----------------
__global__ __launch_bounds__(256) void aev_feat(
    const float* __restrict__ D, const float* __restrict__ S,
    float* __restrict__ feat, int* __restrict__ count, float* __restrict__ GA)
{
    __shared__ float Dm[NA][NA];
    __shared__ float Sv[NA];
    __shared__ int s_T;
    const int tid = threadIdx.x;
    const int cell = blockIdx.x;
    const int b = cell >> 5, i = cell & 31;

    for (int idx = tid; idx < NA * NA; idx += 256)
        ((float*)Dm)[idx] = D[b * NA * NA + idx];
    if (tid < NA) Sv[tid] = S[b * NA + tid];
    if (tid == 0) s_T = 0;
    GA[cell * 256 + tid] = 0.f;
    __syncthreads();

    for (int p = tid; p < NPAIR; p += 256) {
        int rem = p, j = 0;
        while (rem >= 31 - j) { rem -= 31 - j; ++j; }
        const int k = j + 1 + rem;
        const float dij = Dm[i][j], dik = Dm[i][k];
        if (dij < CUTOFF_F && dij != 0.f && dik < CUTOFF_F && dik != 0.f) {
            const int slot = atomicAdd(&s_T, 1);
            const float Rij = dij, Rik = dik, Rjk = Dm[j][k];
            const float zi = Sv[i], zj = Sv[j], zk = Sv[k];
            const float ci = (Rij*Rij + Rik*Rik - Rjk*Rjk) / fmaxf(2.f*Rij*Rik, CLIP_MIN_F);
            const float cj = (Rij*Rij + Rjk*Rjk - Rik*Rik) / fmaxf(2.f*Rij*Rjk, CLIP_MIN_F);
            const float ck = (Rik*Rik + Rjk*Rjk - Rij*Rij) / fmaxf(2.f*Rik*Rjk, CLIP_MIN_F);
            float g0 = Rij + Rik + Rjk;
            float g1 = Rij*Rik + Rij*Rjk + Rik*Rjk;
            float g2 = Rij*Rik*Rjk;
            const float gn = sqrtf(g0*g0 + g1*g1 + g2*g2) + EPS_F;
            float h0 = zi + zj + zk;
            float h1 = ci + cj + ck;
            float h2 = zi*(zj + zk) + zj*zk - ci*(cj + ck) - cj*ck;
            float h3 = zi*(cj + ck) + ci*(zj + zk) + zj*ck + cj*zk;
            float h4 = zi*(zj*zk - cj*ck) - ci*(zj*ck + cj*zk);
            float h5 = zi*(zj*ck + cj*zk) + ci*(zj*zk - cj*ck);
            const float hn = sqrtf(h0*h0 + h1*h1 + h2*h2 + h3*h3 + h4*h4 + h5*h5) + EPS_F;
            const float fcij = 0.5f * cosf(PI_F * Rij / CUTOFF_F) + 0.5f;
            const float fcik = 0.5f * cosf(PI_F * Rik / CUTOFF_F) + 0.5f;
            float* fp = &feat[(cell * SLOT + slot) * FST];
            fp[0] = g0 / gn; fp[1] = g1 / gn; fp[2] = g2 / gn;
            fp[3] = h0 / hn; fp[4] = h1 / hn; fp[5] = h2 / hn;
            fp[6] = h3 / hn; fp[7] = h4 / hn; fp[8] = h5 / hn;
            fp[9] = fcij * fcik;
        }
    }
    __syncthreads();
    if (tid == 0) count[cell] = s_T;
}

// -------- async global->LDS staging (no VGPR payload) --------
__device__ __forceinline__ void cp_async16(const float* g, float* l) {
    __builtin_amdgcn_global_load_lds(
        (const __attribute__((address_space(1))) unsigned int*)g,
        (__attribute__((address_space(3))) unsigned int*)l, 16, 0, 0);
}

// stage one 4096-float (16KB) slice: 4 waves x 4 issues x (64 lanes x 16B)
__device__ __forceinline__ void stage16k(const float* __restrict__ g,
                                         float* __restrict__ buf, int tid) {
    const int lane = tid & 63, w = tid >> 6;
#pragma unroll
    for (int r = 0; r < 4; ++r) {
        const int off = (w * 4 + r) * 256;
        cp_async16(g + off + lane * 4, buf + off);   // LDS base wave-uniform
    }
}

// -------- layer computes (weights + bias from LDS) --------
// 64-out layer: thread = 1 feature x 4 triplets. BOUNDED unroll — full unroll
// lets the scheduler hoist 64 ds_read_b128 and blow the VGPR file (r4/r5 bug).
template<int K, bool RES>
__device__ __forceinline__ void compute64(
    const float* __restrict__ Wl, const float* __restrict__ bl,
    const float* __restrict__ X, float* __restrict__ Y,
    const float* __restrict__ R, int tid)
{
    const int fi = tid & 63;
    const int xo = (tid >> 6) * 4;
    const float bb = bl[fi];
    float a0 = bb, a1 = bb, a2 = bb, a3 = bb;
#pragma unroll 4
    for (int k = 0; k < K; ++k) {
        const float4 xv = *(const float4*)&X[k * XS + xo];   // wave-broadcast
        const float w = Wl[k * 64 + fi];
        a0 += xv.x * w; a1 += xv.y * w; a2 += xv.z * w; a3 += xv.w * w;
    }
    float4 y;
    y.x = tanhf(a0); y.y = tanhf(a1); y.z = tanhf(a2); y.w = tanhf(a3);
    if (RES) {
        const float4 r = *(const float4*)&R[fi * XS + xo];
        y.x += r.x; y.y += r.y; y.z += r.z; y.w += r.w;
    }
    *(float4*)&Y[fi * XS + xo] = y;
}

// 64->128 layer, one 32-row k-slice. Thread = outputs (fo, fo+64) x 4 triplets.
__device__ __forceinline__ void compute5_part(
    const float* __restrict__ Wl /*32 rows x 128*/, const float* __restrict__ X,
    int k0, float (&a0)[4], float (&a1)[4], int tid)
{
    const int fo = tid & 63;
    const int xo = (tid >> 6) * 4;
#pragma unroll 4
    for (int k = 0; k < 32; ++k) {
        const float4 xv = *(const float4*)&X[(k0 + k) * XS + xo];
        const float w0 = Wl[k * 128 + fo];
        const float w1 = Wl[k * 128 + fo + 64];
        a0[0] += xv.x * w0; a0[1] += xv.y * w0; a0[2] += xv.z * w0; a0[3] += xv.w * w0;
        a1[0] += xv.x * w1; a1[1] += xv.y * w1; a1[2] += xv.z * w1; a1[3] += xv.w * w1;
    }
}

// 128->256 layer, one 16-row k-slice. Thread = output f=tid, all 16 triplets.
__device__ __forceinline__ void compute6_part(
    const float* __restrict__ Wl /*16 rows x 256*/, const float* __restrict__ X,
    int k0, float (&a)[16], int tid)
{
#pragma unroll 2
    for (int k = 0; k < 16; ++k) {
        const float w = Wl[k * 256 + tid];
        const float4 x0 = *(const float4*)&X[(k0 + k) * XS + 0];
        const float4 x1 = *(const float4*)&X[(k0 + k) * XS + 4];
        const float4 x2 = *(const float4*)&X[(k0 + k) * XS + 8];
        const float4 x3 = *(const float4*)&X[(k0 + k) * XS + 12];
        a[0]  += x0.x * w; a[1]  += x0.y * w; a[2]  += x0.z * w; a[3]  += x0.w * w;
        a[4]  += x1.x * w; a[5]  += x1.y * w; a[6]  += x1.z * w; a[7]  += x1.w * w;
        a[8]  += x2.x * w; a[9]  += x2.y * w; a[10] += x2.z * w; a[11] += x2.w * w;
        a[12] += x3.x * w; a[13] += x3.y * w; a[14] += x3.z * w; a[15] += x3.w * w;
    }
}

// ---------------- K2: async-pipelined MLP (3-buffer rotation) ----------------
// Schedule: phase i consumes slice s_i from buf[i%3], issues s_{i+2} into
// buf[(i+2)%3] (whose content was consumed at phase i-1, one barrier back).
__global__ __launch_bounds__(256, 2) void aev_mlp(
    const float* __restrict__ feat, const int* __restrict__ count,
    const float* __restrict__ W0, const float* __restrict__ b0,
    const float* __restrict__ W1, const float* __restrict__ b1,
    const float* __restrict__ W2, const float* __restrict__ b2,
    const float* __restrict__ W3, const float* __restrict__ b3,
    const float* __restrict__ W4, const float* __restrict__ b4,
    const float* __restrict__ W5, const float* __restrict__ b5,
    const float* __restrict__ W6, const float* __restrict__ b6,
    float* __restrict__ GA)
{
    __shared__ __align__(16) float WB0[4096];
    __shared__ __align__(16) float WB1[4096];
    __shared__ __align__(16) float WB2[4096];
    __shared__ __align__(16) float Xs[9 * XS];
    __shared__ __align__(16) float U0[64 * XS];
    __shared__ __align__(16) float U1[64 * XS];
    __shared__ __align__(16) float U2[64 * XS];
    __shared__ __align__(16) float U3[128 * XS];
    __shared__ float wsh[TC];
    __shared__ float bsh[704];   // b0..b4 @0..319, b5 @320, b6 @448

    const int tid = threadIdx.x;
    const int cell = blockIdx.x & 255;
    const int q = blockIdx.x >> 8;
    const int T = count[cell];
    const int nch = (T + TC - 1) / TC;
    if (q >= nch) return;        // block-uniform exit (no barriers yet)

    if (tid < 64) {
        bsh[tid]       = b0[tid];
        bsh[64 + tid]  = b1[tid];
        bsh[128 + tid] = b2[tid];
        bsh[192 + tid] = b3[tid];
        bsh[256 + tid] = b4[tid];
    }
    if (tid < 128) bsh[320 + tid] = b5[tid];
    bsh[448 + tid] = b6[tid];

    float gacc = 0.f;

    for (int c = q; c < nch; c += NQ) {
        const int t0 = c * TC;

        // ---- prologue: W0->WB0 (sync, 2.3KB), issue W1->WB1, load features ----
        stage16k(W1, WB1, tid);
        if (tid < 144) ((float4*)WB0)[tid] = ((const float4*)W0)[tid];
        if (tid < TC * FST) {   // contiguous 160 floats
            const int t = tid / FST, qf = tid % FST;
            const int slot = t0 + t;
            const float v = (slot < T) ? feat[(cell * SLOT + t0) * FST + tid] : 0.f;
            if (qf == 9) wsh[t] = v; else Xs[qf * XS + t] = v;
        }
        __syncthreads();

        // ph0: L0 (WB0); issue W2->WB2
        stage16k(W2, WB2, tid);
        compute64<9,  false>(WB0, bsh + 0,   Xs, U0, nullptr, tid);
        __syncthreads();
        // ph1: L1 (WB1, res U0); issue W3->WB0
        stage16k(W3, WB0, tid);
        compute64<64, true >(WB1, bsh + 64,  U0, U1, U0, tid);       // xb1 -> U1
        __syncthreads();
        // ph2: L2 (WB2); issue W4->WB1
        stage16k(W4, WB1, tid);
        compute64<64, false>(WB2, bsh + 128, U1, U2, nullptr, tid);  // x2 -> U2
        __syncthreads();
        // ph3: L3 (WB0); issue W5a->WB2
        stage16k(W5, WB2, tid);
        compute64<64, false>(WB0, bsh + 192, U2, U0, nullptr, tid);  // x3 -> U0
        __syncthreads();
        // ph4: L4 (WB1, res U1); issue W5b->WB0
        stage16k(W5 + 4096, WB0, tid);
        compute64<64, true >(WB1, bsh + 256, U0, U2, U1, tid);       // xb2 -> U2
        __syncthreads();

        // ---- L5: 2 k-slices, persistent accumulators ----
        float a0[4], a1[4];
        {
            const int fo = tid & 63;
            const float bb0 = bsh[320 + fo], bb1 = bsh[320 + fo + 64];
#pragma unroll
            for (int r = 0; r < 4; ++r) { a0[r] = bb0; a1[r] = bb1; }
        }
        // ph5: L5a (WB2); issue W6 s0->WB1
        stage16k(W6, WB1, tid);
        compute5_part(WB2, U2, 0, a0, a1, tid);
        __syncthreads();
        // ph6: L5b (WB0), tanh -> U3; issue W6 s1->WB2
        stage16k(W6 + 4096, WB2, tid);
        compute5_part(WB0, U2, 32, a0, a1, tid);
        {
            const int fo = tid & 63;
            const int xo = (tid >> 6) * 4;
            float4 y0, y1;
            y0.x = tanhf(a0[0]); y0.y = tanhf(a0[1]); y0.z = tanhf(a0[2]); y0.w = tanhf(a0[3]);
            y1.x = tanhf(a1[0]); y1.y = tanhf(a1[1]); y1.z = tanhf(a1[2]); y1.w = tanhf(a1[3]);
            *(float4*)&U3[fo * XS + xo] = y0;
            *(float4*)&U3[(fo + 64) * XS + xo] = y1;
        }
        __syncthreads();

        // ---- L6: 8 k-slices of 16 rows; thread = output f=tid x 16 triplets ----
        float a6[16];
        {
            const float bb = bsh[448 + tid];
#pragma unroll
            for (int r = 0; r < 16; ++r) a6[r] = bb;
        }
        // ph7: s0 (WB1); issue s2->WB0
        stage16k(W6 + 2 * 4096, WB0, tid);
        compute6_part(WB1, U3, 0, a6, tid);
        __syncthreads();
        // ph8: s1 (WB2); issue s3->WB1
        stage16k(W6 + 3 * 4096, WB1, tid);
        compute6_part(WB2, U3, 16, a6, tid);
        __syncthreads();
        // ph9: s2 (WB0); issue s4->WB2
        stage16k(W6 + 4 * 4096, WB2, tid);
        compute6_part(WB0, U3, 32, a6, tid);
        __syncthreads();
        // ph10: s3 (WB1); issue s5->WB0
        stage16k(W6 + 5 * 4096, WB0, tid);
        compute6_part(WB1, U3, 48, a6, tid);
        __syncthreads();
        // ph11: s4 (WB2); issue s6->WB1
        stage16k(W6 + 6 * 4096, WB1, tid);
        compute6_part(WB2, U3, 64, a6, tid);
        __syncthreads();
        // ph12: s5 (WB0); issue s7->WB2
        stage16k(W6 + 7 * 4096, WB2, tid);
        compute6_part(WB0, U3, 80, a6, tid);
        __syncthreads();
        // ph13: s6 (WB1)
        compute6_part(WB1, U3, 96, a6, tid);
        __syncthreads();
        // ph14: s7 (WB2)
        compute6_part(WB2, U3, 112, a6, tid);

        // finalize: weighted tanh sum into register accumulator
#pragma unroll 4
        for (int r = 0; r < 16; ++r)
            gacc += wsh[r] * tanhf(a6[r]);
        __syncthreads();   // protect wsh/Xs/WB1 before next chunk overwrites
    }

    atomicAdd(&GA[cell * 256 + tid], gacc);
}

// ---------------- K3: normalize ----------------
__global__ __launch_bounds__(256) void aev_norm(
    const float* __restrict__ GA, float* __restrict__ out)
{
    __shared__ float wred[4];
    const int tid = threadIdx.x;
    const int cell = blockIdx.x;
    const float v = GA[cell * 256 + tid];
    float ss = v * v;
#pragma unroll
    for (int off = 32; off > 0; off >>= 1) ss += __shfl_down(ss, off);
    if ((tid & 63) == 0) wred[tid >> 6] = ss;
    __syncthreads();
    const float tot = wred[0] + wred[1] + wred[2] + wred[3];
    out[cell * 256 + tid] = v / (sqrtf(tot) + EPS_F);
}

extern "C" void kernel_launch(void* const* d_in, const int* in_sizes, int n_in,
                              void* d_out, int out_size, void* d_ws, size_t ws_size,
                              hipStream_t stream)
{
    const float* D  = (const float*)d_in[0];
    const float* S  = (const float*)d_in[1];
    const float* W0 = (const float*)d_in[2];  const float* b0 = (const float*)d_in[3];
    const float* W1 = (const float*)d_in[4];  const float* b1 = (const float*)d_in[5];
    const float* W2 = (const float*)d_in[6];  const float* b2 = (const float*)d_in[7];
    const float* W3 = (const float*)d_in[8];  const float* b3 = (const float*)d_in[9];
    const float* W4 = (const float*)d_in[10]; const float* b4 = (const float*)d_in[11];
    const float* W5 = (const float*)d_in[12]; const float* b5 = (const float*)d_in[13];
    const float* W6 = (const float*)d_in[14]; const float* b6 = (const float*)d_in[15];
    float* out = (float*)d_out;

    float* feat  = (float*)d_ws;                        // 256*496*10 floats
    int*   count = (int*)(feat + NCELL * SLOT * FST);   // 256 ints
    float* GA    = (float*)(count + 256);               // 256*256 floats

    aev_feat<<<dim3(NCELL), dim3(256), 0, stream>>>(D, S, feat, count, GA);
    aev_mlp<<<dim3(NCELL * NQ), dim3(256), 0, stream>>>(
        feat, count, W0, b0, W1, b1, W2, b2, W3, b3, W4, b4, W5, b5, W6, b6, GA);
    aev_norm<<<dim3(NCELL), dim3(256), 0, stream>>>(GA, out);
}